// Round 8
// baseline (206.198 us; speedup 1.0000x reference)
//
#include <hip/hip_runtime.h>
#include <hip/hip_bf16.h>

// ---- problem constants ----
#define NN 25000
#define PP 100000
#define TT 4
#define DD 128
#define LEAKY 0.001f

#define PB 32          // propers per block
#define ROWS 128       // PB * TT rows of the MLP per block

typedef __bf16 bf16;
typedef __bf16 bf16x8 __attribute__((ext_vector_type(8)));
typedef float  f32x4  __attribute__((ext_vector_type(4)));

// ---- workspace layout (bytes) ----
// Weight tables in FRAGMENT ORDER: chunks of [64 lanes][8 bf16], one
// global_load_dwordx4 per wave = one contiguous 1 KB chunk.
#define OFF_ENCB  0u                    // 25000*128 bf16 = 6,400,000 B
#define OFF_W0SW  6400000u              // 128 chunks * 1KB
#define OFF_W1SW  6531072u              // 32 chunks * 1KB
#define OFF_W2SW  6563840u              // 32 chunks * 1KB
#define OFF_W3SW  6596608u              // 4 chunks * 1KB
#define WS_END    6600704u

// prep work partition (thread counts)
#define PR_ENCB4 800000
#define PR_W0SW  65536
#define PR_W1SW  16384
#define PR_W2SW  16384
#define PR_W3SW  2048
#define PR_COPY4 75000
#define PR_TOTAL (PR_ENCB4 + PR_W0SW + PR_W1SW + PR_W2SW + PR_W3SW + PR_COPY4)

__global__ __launch_bounds__(256) void prep_kernel(
    const float* __restrict__ encoded, const float* __restrict__ W0,
    const float* __restrict__ W1, const float* __restrict__ W2,
    const float* __restrict__ W3, const float* __restrict__ answer,
    bf16* __restrict__ encB, bf16* __restrict__ W0sw, bf16* __restrict__ W1sw,
    bf16* __restrict__ W2sw, bf16* __restrict__ W3sw, float* __restrict__ out)
{
    int idx = blockIdx.x * 256 + threadIdx.x;
    if (idx < PR_ENCB4) {               // float4 -> 4x bf16 (8 B store)
        float4 v = ((const float4*)encoded)[idx];
        bf16 pk[4] = {(bf16)v.x, (bf16)v.y, (bf16)v.z, (bf16)v.w};
        *(uint2*)(encB + idx * 4) = *(const uint2*)pk;
        return;
    }
    idx -= PR_ENCB4;
    if (idx < PR_W0SW) {
        int j = idx & 7, lane = (idx >> 3) & 63, c = idx >> 9;
        int fr = lane & 15, quad = lane >> 4;
        int kc = c & 15, iwv = c >> 4;
        int k = kc * 32 + quad * 8 + j;
        W0sw[idx] = (bf16)W0[k * 128 + iwv * 16 + fr];
        return;
    }
    idx -= PR_W0SW;
    if (idx < PR_W1SW) {
        int j = idx & 7, lane = (idx >> 3) & 63, c = idx >> 9;
        int fr = lane & 15, quad = lane >> 4;
        int kc = c & 3, nt = c >> 2;
        int k = kc * 32 + quad * 8 + j;
        W1sw[idx] = (bf16)W1[k * 128 + nt * 16 + fr];
        return;
    }
    idx -= PR_W1SW;
    if (idx < PR_W2SW) {
        int j = idx & 7, lane = (idx >> 3) & 63, c = idx >> 9;
        int fr = lane & 15, quad = lane >> 4;
        int kc = c & 3, nt = c >> 2;
        int k = kc * 32 + quad * 8 + j;
        W2sw[idx] = (bf16)W2[k * 128 + nt * 16 + fr];
        return;
    }
    idx -= PR_W2SW;
    if (idx < PR_W3SW) {
        int j = idx & 7, lane = (idx >> 3) & 63, kc = idx >> 9;
        int fr = lane & 15, quad = lane >> 4;
        int k = kc * 32 + quad * 8 + j;
        W3sw[idx] = (fr < 2) ? (bf16)W3[k * 2 + fr] : (bf16)0.0f;
        return;
    }
    idx -= PR_W3SW;
    if (idx < PR_COPY4) { ((float4*)out)[idx] = ((const float4*)answer)[idx]; }
}

// PB=32, 512 threads, ping-pong H buffers: 5 barriers per 32 propers (vs 18
// in the R7 structure). LDS ~74.2 KB -> 2 blocks/CU (16 waves/CU — R6 vs R7
// showed waves beyond 16 buy ~3%; barrier density is the limiter).
// __launch_bounds__(512,4): 128-reg budget -> zero spill guaranteed (R4/R5/R7
// showed any tighter budget spills); occupancy is LDS-capped at the same
// 2 blocks/CU regardless.
__global__ __launch_bounds__(512, 4) void main_kernel(
    const float* __restrict__ coords, const int* __restrict__ propers,
    const float* __restrict__ tvec, const float* __restrict__ W0,
    const float* __restrict__ b0, const float* __restrict__ b1,
    const float* __restrict__ b2, const float* __restrict__ b3,
    const bf16* __restrict__ encB, const bf16* __restrict__ W0sw,
    const bf16* __restrict__ W1sw, const bf16* __restrict__ W2sw,
    const bf16* __restrict__ W3sw, float* __restrict__ out)
{
    // buf0 holds H0 then H2; buf1 holds sA (phase 1-2) then H1. sA (32x520 =
    // 16640 elems) fits in buf1 (17408 elems) and is dead before buf1's
    // first H1 write (which happens after B2, by when all waves' phase-2 sA
    // reads are complete).
    __shared__ bf16 sBuf0[ROWS * 136];   // 34816 B
    __shared__ bf16 sBuf1[ROWS * 136];   // 34816 B
    #define SA(p, c)  sBuf1[(p) * 520 + (c)]
    #define SH0(r, j) sBuf0[(r) * 136 + (j)]
    #define SH1(r, j) sBuf1[(r) * 136 + (j)]
    __shared__ int   sNodes[PB][4];
    __shared__ float sSn[ROWS], sCs[ROWS], sDl[ROWS], sDh[ROWS][3];
    __shared__ float sDelta[ROWS][2];

    const int tid  = threadIdx.x;
    const int pBase = blockIdx.x * PB;
    const float tv0 = tvec[0], tv1 = tvec[1], tv2 = tvec[2], tv3 = tvec[3];

    // ---- phase 1: stage sA (all 512) + geometry (tid<128) ----
    {   // sA: 128 (p,i) rows of 256 B; 4 threads per row (64 B each)
        int row = tid >> 2, sg = tid & 3;
        int p = row >> 2, i = row & 3;
        int node = propers[(pBase + p) * 4 + i];
        if (sg == 0) sNodes[p][i] = node;
        const uint4* src = (const uint4*)(encB + (size_t)node * 128 + sg * 32);
        uint4* dst = (uint4*)(&SA(p, i * 128 + sg * 32));
        #pragma unroll
        for (int q = 0; q < 4; ++q) dst[q] = src[q];
    }
    if (tid < ROWS) {
        int r = tid, p = r >> 2, t = r & 3;
        const int* prow = propers + (pBase + p) * 4;
        int n0 = prow[0], n1 = prow[1], n2 = prow[2], n3 = prow[3];
        const float* c0 = coords + n0 * 12 + t * 3;
        const float* c1 = coords + n1 * 12 + t * 3;
        const float* c2 = coords + n2 * 12 + t * 3;
        const float* c3 = coords + n3 * 12 + t * 3;
        float u1x = c1[0]-c0[0], u1y = c1[1]-c0[1], u1z = c1[2]-c0[2];
        float u2x = c2[0]-c1[0], u2y = c2[1]-c1[1], u2z = c2[2]-c1[2];
        float u3x = c3[0]-c2[0], u3y = c3[1]-c2[1], u3z = c3[2]-c2[2];
        float ax = u1y*u2z - u1z*u2y, ay = u1z*u2x - u1x*u2z, az = u1x*u2y - u1y*u2x;
        float bx = u2y*u3z - u2z*u3y, by = u2z*u3x - u2x*u3z, bz = u2x*u3y - u2y*u3x;
        float u2n = sqrtf(u2x*u2x + u2y*u2y + u2z*u2z);
        float num = u2n * (u1x*bx + u1y*by + u1z*bz);
        float den = ax*bx + ay*by + az*bz;
        float hyp = sqrtf(num*num + den*den);
        float sn, cs;
        if (hyp > 1e-30f) { float ih = 1.0f / hyp; sn = num * ih; cs = den * ih; }
        else { sn = 0.0f; cs = 1.0f; }
        float drx = c0[0]-c3[0], dry = c0[1]-c3[1], drz = c0[2]-c3[2];
        float dl = sqrtf(fmaxf(drx*drx + dry*dry + drz*drz, 1e-12f));
        float il = 1.0f / dl;
        sSn[r] = sn; sCs[r] = cs; sDl[r] = dl;
        sDh[r][0] = drx * il; sDh[r][1] = dry * il; sDh[r][2] = drz * il;
    }
    __syncthreads();   // B1: sA + geometry ready

    const int wv = tid >> 6, lane = tid & 63;
    const int fr = lane & 15;      // free-dim index of A/B frags and C/D column
    const int quad = lane >> 4;

    // ---- phase 2: g-GEMM, M=32 (2 M-tiles), N=128 (16 cols/wave), K=512 ----
    f32x4 acc0 = {0.f,0.f,0.f,0.f}, acc1 = {0.f,0.f,0.f,0.f};
    {
        const bf16* aB0 = &SA(fr, quad * 8);        // propers 0..15
        const bf16* aB1 = &SA(16 + fr, quad * 8);   // propers 16..31
        const bf16* w0b = W0sw + (size_t)wv * 16 * 512 + lane * 8;  // iwv == wv
        #pragma unroll
        for (int kc = 0; kc < 16; ++kc) {
            bf16x8 bF  = *(const bf16x8*)(w0b + kc * 512);
            bf16x8 aF0 = *(const bf16x8*)(aB0 + kc * 32);
            bf16x8 aF1 = *(const bf16x8*)(aB1 + kc * 32);
            acc0 = __builtin_amdgcn_mfma_f32_16x16x32_bf16(aF0, bF, acc0, 0, 0, 0);
            acc1 = __builtin_amdgcn_mfma_f32_16x16x32_bf16(aF1, bF, acc1, 0, 0, 0);
        }
    }
    // ---- h0 epilogue: rank-4 features + bias, leaky -> SH0 (buf0; no barrier
    //      needed — phase-2 reads are from buf1) ----
    {
        int j = wv * 16 + fr;                            // output column
        float w512 = W0[512 * 128 + j], w513 = W0[513 * 128 + j];
        float w514 = W0[514 * 128 + j], w515 = W0[515 * 128 + j];
        float bb = b0[j];
        #pragma unroll
        for (int s = 0; s < 2; ++s) {
            const f32x4 a = s ? acc1 : acc0;
            #pragma unroll
            for (int reg = 0; reg < 4; ++reg) {
                int p = s * 16 + quad * 4 + reg;         // C/D row = proper
                float g = a[reg] + bb;
                #pragma unroll
                for (int t = 0; t < 4; ++t) {
                    int r = p * 4 + t;
                    float tvv = (t == 0) ? tv0 : (t == 1) ? tv1 : (t == 2) ? tv2 : tv3;
                    float v = g + tvv * w512 + sSn[r] * w513 + sCs[r] * w514 + sDl[r] * w515;
                    v = fmaxf(v, LEAKY * v);
                    SH0(r, j) = (bf16)v;
                }
            }
        }
    }
    __syncthreads();   // B2: H0 ready (and all sA reads complete -> buf1 free)

    const int m2 = (wv & 3) * 2;   // first of 2 M-tiles for phases 3/4
    const int nh = wv >> 2;        // N-half (cols nh*64..+63)

    // ---- phase 3: h1 = leaky(h0 @ W1 + b1); read SH0, write SH1 ----
    #pragma unroll
    for (int s = 0; s < 2; ++s) {
        f32x4 hacc[4];
        #pragma unroll
        for (int nt = 0; nt < 4; ++nt) hacc[nt] = (f32x4){0.f,0.f,0.f,0.f};
        const bf16* aRow = &SH0((m2 + s) * 16 + fr, quad * 8);
        const bf16* w1b = W1sw + lane * 8;
        #pragma unroll
        for (int kc = 0; kc < 4; ++kc) {
            bf16x8 aF = *(const bf16x8*)(aRow + kc * 32);
            #pragma unroll
            for (int nt = 0; nt < 4; ++nt) {
                bf16x8 bF = *(const bf16x8*)(w1b + ((nh * 4 + nt) * 4 + kc) * 512);
                hacc[nt] = __builtin_amdgcn_mfma_f32_16x16x32_bf16(aF, bF, hacc[nt], 0, 0, 0);
            }
        }
        #pragma unroll
        for (int nt = 0; nt < 4; ++nt) {
            int j = (nh * 4 + nt) * 16 + fr;
            float bb = b1[j];
            #pragma unroll
            for (int reg = 0; reg < 4; ++reg) {
                int r = (m2 + s) * 16 + quad * 4 + reg;
                float v = hacc[nt][reg] + bb;
                v = fmaxf(v, LEAKY * v);
                SH1(r, j) = (bf16)v;
            }
        }
    }
    __syncthreads();   // B3: H1 ready (and all H0 reads complete -> buf0 free)

    // ---- phase 4: h2 = leaky(h1 @ W2 + b2); read SH1, write SH0 ----
    #pragma unroll
    for (int s = 0; s < 2; ++s) {
        f32x4 hacc[4];
        #pragma unroll
        for (int nt = 0; nt < 4; ++nt) hacc[nt] = (f32x4){0.f,0.f,0.f,0.f};
        const bf16* aRow = &SH1((m2 + s) * 16 + fr, quad * 8);
        const bf16* w2b = W2sw + lane * 8;
        #pragma unroll
        for (int kc = 0; kc < 4; ++kc) {
            bf16x8 aF = *(const bf16x8*)(aRow + kc * 32);
            #pragma unroll
            for (int nt = 0; nt < 4; ++nt) {
                bf16x8 bF = *(const bf16x8*)(w2b + ((nh * 4 + nt) * 4 + kc) * 512);
                hacc[nt] = __builtin_amdgcn_mfma_f32_16x16x32_bf16(aF, bF, hacc[nt], 0, 0, 0);
            }
        }
        #pragma unroll
        for (int nt = 0; nt < 4; ++nt) {
            int j = (nh * 4 + nt) * 16 + fr;
            float bb = b2[j];
            #pragma unroll
            for (int reg = 0; reg < 4; ++reg) {
                int r = (m2 + s) * 16 + quad * 4 + reg;
                float v = hacc[nt][reg] + bb;
                v = fmaxf(v, LEAKY * v);
                SH0(r, j) = (bf16)v;
            }
        }
    }
    __syncthreads();   // B4: H2 ready

    // ---- phase 5: delta = h2 @ W3 + b3 (zero-padded to 16 cols); all 8 waves ----
    {
        f32x4 dacc = {0.f,0.f,0.f,0.f};
        const bf16* aRow = &SH0(wv * 16 + fr, quad * 8);
        const bf16* w3b = W3sw + lane * 8;
        #pragma unroll
        for (int kc = 0; kc < 4; ++kc) {
            bf16x8 aF = *(const bf16x8*)(aRow + kc * 32);
            bf16x8 bF = *(const bf16x8*)(w3b + kc * 512);
            dacc = __builtin_amdgcn_mfma_f32_16x16x32_bf16(aF, bF, dacc, 0, 0, 0);
        }
        if (fr < 2) {
            float bb = b3[fr];
            #pragma unroll
            for (int reg = 0; reg < 4; ++reg)
                sDelta[wv * 16 + quad * 4 + reg][fr] = dacc[reg] + bb;
        }
    }
    __syncthreads();   // B5: delta ready

    // ---- phase 6: scatter-add (6 atomics per row, 768 total) ----
    for (int idx = tid; idx < ROWS * 6; idx += 512) {
        int r = idx / 6, c = idx % 6;
        int p = r >> 2, t = r & 3;
        int side = c / 3, ax = c % 3;
        int node = sNodes[p][side ? 3 : 0];
        float dval = side ? 0.5f * sDelta[r][1] : -0.5f * sDelta[r][0];
        atomicAdd(out + node * 12 + t * 3 + ax, dval * sDh[r][ax]);
    }
    #undef SA
    #undef SH0
    #undef SH1
}

extern "C" void kernel_launch(void* const* d_in, const int* in_sizes, int n_in,
                              void* d_out, int out_size, void* d_ws, size_t ws_size,
                              hipStream_t stream) {
    const float* coords  = (const float*)d_in[0];
    const int*   propers = (const int*)d_in[1];
    const float* encoded = (const float*)d_in[2];
    const float* tvec    = (const float*)d_in[3];
    const float* answer  = (const float*)d_in[4];
    const float* W0 = (const float*)d_in[5];
    const float* b0 = (const float*)d_in[6];
    const float* W1 = (const float*)d_in[7];
    const float* b1 = (const float*)d_in[8];
    const float* W2 = (const float*)d_in[9];
    const float* b2 = (const float*)d_in[10];
    const float* W3 = (const float*)d_in[11];
    const float* b3 = (const float*)d_in[12];
    float* out = (float*)d_out;
    char* ws = (char*)d_ws;
    bf16* encB = (bf16*)(ws + OFF_ENCB);
    bf16* W0sw = (bf16*)(ws + OFF_W0SW);
    bf16* W1sw = (bf16*)(ws + OFF_W1SW);
    bf16* W2sw = (bf16*)(ws + OFF_W2SW);
    bf16* W3sw = (bf16*)(ws + OFF_W3SW);

    int prep_blocks = (PR_TOTAL + 255) / 256;
    prep_kernel<<<prep_blocks, 256, 0, stream>>>(encoded, W0, W1, W2, W3, answer,
                                                 encB, W0sw, W1sw, W2sw, W3sw, out);
    main_kernel<<<PP / PB, 512, 0, stream>>>(coords, propers, tvec, W0, b0, b1, b2, b3,
                                             encB, W0sw, W1sw, W2sw, W3sw, out);
}

// Round 9
// 204.879 us; speedup vs baseline: 1.0064x; 1.0064x over previous
//
#include <hip/hip_runtime.h>
#include <hip/hip_bf16.h>

// ---- problem constants ----
#define NN 25000
#define PP 100000
#define TT 4
#define DD 128
#define LEAKY 0.001f

#define PB 32          // propers per block
#define ROWS 128       // PB * TT rows of the MLP per block

typedef __bf16 bf16;
typedef __bf16 bf16x8 __attribute__((ext_vector_type(8)));
typedef float  f32x4  __attribute__((ext_vector_type(4)));

// ---- workspace layout (bytes) ----
#define OFF_ENCB  0u                    // 25000*128 bf16 = 6,400,000 B
#define OFF_W0SW  6400000u              // 128 chunks * 1KB (fragment order)
#define OFF_W1SW  6531072u              // 32 chunks * 1KB
#define OFF_W2SW  6563840u              // 32 chunks * 1KB
#define OFF_W3SW  6596608u              // 4 chunks * 1KB
#define OFF_E     6600704u              // 4 tables [NN][128] bf16 = 25,600,000 B
#define WS_END    32200704u

// prep work partition (thread counts)
#define PR_ENCB4 800000
#define PR_W0SW  65536
#define PR_W1SW  16384
#define PR_W2SW  16384
#define PR_W3SW  2048
#define PR_COPY4 75000
#define PR_TOTAL (PR_ENCB4 + PR_W0SW + PR_W1SW + PR_W2SW + PR_W3SW + PR_COPY4)

__global__ __launch_bounds__(256) void prep_kernel(
    const float* __restrict__ encoded, const float* __restrict__ W0,
    const float* __restrict__ W1, const float* __restrict__ W2,
    const float* __restrict__ W3, const float* __restrict__ answer,
    bf16* __restrict__ encB, bf16* __restrict__ W0sw, bf16* __restrict__ W1sw,
    bf16* __restrict__ W2sw, bf16* __restrict__ W3sw, float* __restrict__ out)
{
    int idx = blockIdx.x * 256 + threadIdx.x;
    if (idx < PR_ENCB4) {               // float4 -> 4x bf16 (8 B store)
        float4 v = ((const float4*)encoded)[idx];
        bf16 pk[4] = {(bf16)v.x, (bf16)v.y, (bf16)v.z, (bf16)v.w};
        *(uint2*)(encB + idx * 4) = *(const uint2*)pk;
        return;
    }
    idx -= PR_ENCB4;
    if (idx < PR_W0SW) {
        int j = idx & 7, lane = (idx >> 3) & 63, c = idx >> 9;
        int fr = lane & 15, quad = lane >> 4;
        int kc = c & 15, iwv = c >> 4;
        int k = kc * 32 + quad * 8 + j;
        W0sw[idx] = (bf16)W0[k * 128 + iwv * 16 + fr];
        return;
    }
    idx -= PR_W0SW;
    if (idx < PR_W1SW) {
        int j = idx & 7, lane = (idx >> 3) & 63, c = idx >> 9;
        int fr = lane & 15, quad = lane >> 4;
        int kc = c & 3, nt = c >> 2;
        int k = kc * 32 + quad * 8 + j;
        W1sw[idx] = (bf16)W1[k * 128 + nt * 16 + fr];
        return;
    }
    idx -= PR_W1SW;
    if (idx < PR_W2SW) {
        int j = idx & 7, lane = (idx >> 3) & 63, c = idx >> 9;
        int fr = lane & 15, quad = lane >> 4;
        int kc = c & 3, nt = c >> 2;
        int k = kc * 32 + quad * 8 + j;
        W2sw[idx] = (bf16)W2[k * 128 + nt * 16 + fr];
        return;
    }
    idx -= PR_W2SW;
    if (idx < PR_W3SW) {
        int j = idx & 7, lane = (idx >> 3) & 63, kc = idx >> 9;
        int fr = lane & 15, quad = lane >> 4;
        int k = kc * 32 + quad * 8 + j;
        W3sw[idx] = (fr < 2) ? (bf16)W3[k * 2 + fr] : (bf16)0.0f;
        return;
    }
    idx -= PR_W3SW;
    if (idx < PR_COPY4) { ((float4*)out)[idx] = ((const float4*)answer)[idx]; }
}

// E_i[n][j] = sum_k enc[n][k] * W0[i*128+k][j]  (i=0..3), bf16 output.
// 16 node-rows per block; 8 waves cover j = wv*16+fr; K=128 per table via
// W0sw fragment chunks kc = i*4 + kcc.
__global__ __launch_bounds__(512, 4) void prep_e_kernel(
    const bf16* __restrict__ encB, const bf16* __restrict__ W0sw,
    bf16* __restrict__ E)
{
    __shared__ bf16 sA[16][136];
    const int tid = threadIdx.x;
    const int row0 = blockIdx.x * 16;
    if (tid < 256) {                     // stage 16 rows x 128 bf16
        int row = tid >> 4, seg = tid & 15;
        int rr = row0 + row; if (rr > NN - 1) rr = NN - 1;
        *(bf16x8*)(&sA[row][seg * 8]) =
            *(const bf16x8*)(encB + (size_t)rr * 128 + seg * 8);
    }
    __syncthreads();
    const int wv = tid >> 6, lane = tid & 63;
    const int fr = lane & 15, quad = lane >> 4;
    const bf16* aBase = &sA[fr][quad * 8];
    #pragma unroll
    for (int i = 0; i < 4; ++i) {
        f32x4 dacc = {0.f, 0.f, 0.f, 0.f};
        #pragma unroll
        for (int kcc = 0; kcc < 4; ++kcc) {
            bf16x8 aF = *(const bf16x8*)(aBase + kcc * 32);
            bf16x8 bF = *(const bf16x8*)(W0sw + ((size_t)wv * 16 + i * 4 + kcc) * 512 + lane * 8);
            dacc = __builtin_amdgcn_mfma_f32_16x16x32_bf16(aF, bF, dacc, 0, 0, 0);
        }
        #pragma unroll
        for (int reg = 0; reg < 4; ++reg) {
            int row = row0 + quad * 4 + reg;
            if (row < NN)
                E[((size_t)i * NN + row) * 128 + wv * 16 + fr] = (bf16)dacc[reg];
        }
    }
}

// Main: phase-2 g-GEMM replaced by E-table gather+sum (no sA staging, no
// K=512 MFMA chain). 5 barriers. LDS ~74 KB -> 2 blocks/CU.
// (512,4): 128-reg budget, proven spill-free.
__global__ __launch_bounds__(512, 4) void main_kernel(
    const float* __restrict__ coords, const int* __restrict__ propers,
    const float* __restrict__ tvec, const float* __restrict__ W0,
    const float* __restrict__ b0, const float* __restrict__ b1,
    const float* __restrict__ b2, const float* __restrict__ b3,
    const bf16* __restrict__ E, const bf16* __restrict__ W1sw,
    const bf16* __restrict__ W2sw, const bf16* __restrict__ W3sw,
    float* __restrict__ out)
{
    __shared__ bf16 sBuf0[ROWS * 136];   // H0 then H2
    __shared__ bf16 sBuf1[ROWS * 136];   // H1
    #define SH0(r, j) sBuf0[(r) * 136 + (j)]
    #define SH1(r, j) sBuf1[(r) * 136 + (j)]
    __shared__ int   sNodes[PB][4];
    __shared__ float sSn[ROWS], sCs[ROWS], sDl[ROWS], sDh[ROWS][3];
    __shared__ float sDelta[ROWS][2];

    const int tid  = threadIdx.x;
    const int pBase = blockIdx.x * PB;
    const float tv0 = tvec[0], tv1 = tvec[1], tv2 = tvec[2], tv3 = tvec[3];

    // ---- phase 1: E gather (all 512) + geometry (tid<128) ----
    const int p  = tid >> 4, s8 = tid & 15;          // 16 threads per proper
    bf16x8 e0, e1, e2, e3;
    float w512v[8], w513v[8], w514v[8], w515v[8], b0v[8];
    {
        const int* prow = propers + (pBase + p) * 4;
        int n0 = prow[0], n1 = prow[1], n2 = prow[2], n3 = prow[3];
        e0 = *(const bf16x8*)(E + ((size_t)0 * NN + n0) * 128 + s8 * 8);
        e1 = *(const bf16x8*)(E + ((size_t)1 * NN + n1) * 128 + s8 * 8);
        e2 = *(const bf16x8*)(E + ((size_t)2 * NN + n2) * 128 + s8 * 8);
        e3 = *(const bf16x8*)(E + ((size_t)3 * NN + n3) * 128 + s8 * 8);
        *(float4*)(w512v)     = *(const float4*)(W0 + 512 * 128 + s8 * 8);
        *(float4*)(w512v + 4) = *(const float4*)(W0 + 512 * 128 + s8 * 8 + 4);
        *(float4*)(w513v)     = *(const float4*)(W0 + 513 * 128 + s8 * 8);
        *(float4*)(w513v + 4) = *(const float4*)(W0 + 513 * 128 + s8 * 8 + 4);
        *(float4*)(w514v)     = *(const float4*)(W0 + 514 * 128 + s8 * 8);
        *(float4*)(w514v + 4) = *(const float4*)(W0 + 514 * 128 + s8 * 8 + 4);
        *(float4*)(w515v)     = *(const float4*)(W0 + 515 * 128 + s8 * 8);
        *(float4*)(w515v + 4) = *(const float4*)(W0 + 515 * 128 + s8 * 8 + 4);
        *(float4*)(b0v)       = *(const float4*)(b0 + s8 * 8);
        *(float4*)(b0v + 4)   = *(const float4*)(b0 + s8 * 8 + 4);
    }
    if (tid < PB * 4) sNodes[tid >> 2][tid & 3] = propers[(pBase + (tid >> 2)) * 4 + (tid & 3)];
    if (tid < ROWS) {
        int r = tid, pp = r >> 2, t = r & 3;
        const int* prow = propers + (pBase + pp) * 4;
        int n0 = prow[0], n1 = prow[1], n2 = prow[2], n3 = prow[3];
        const float* c0 = coords + n0 * 12 + t * 3;
        const float* c1 = coords + n1 * 12 + t * 3;
        const float* c2 = coords + n2 * 12 + t * 3;
        const float* c3 = coords + n3 * 12 + t * 3;
        float u1x = c1[0]-c0[0], u1y = c1[1]-c0[1], u1z = c1[2]-c0[2];
        float u2x = c2[0]-c1[0], u2y = c2[1]-c1[1], u2z = c2[2]-c1[2];
        float u3x = c3[0]-c2[0], u3y = c3[1]-c2[1], u3z = c3[2]-c2[2];
        float ax = u1y*u2z - u1z*u2y, ay = u1z*u2x - u1x*u2z, az = u1x*u2y - u1y*u2x;
        float bx = u2y*u3z - u2z*u3y, by = u2z*u3x - u2x*u3z, bz = u2x*u3y - u2y*u3x;
        float u2n = sqrtf(u2x*u2x + u2y*u2y + u2z*u2z);
        float num = u2n * (u1x*bx + u1y*by + u1z*bz);
        float den = ax*bx + ay*by + az*bz;
        float hyp = sqrtf(num*num + den*den);
        float sn, cs;
        if (hyp > 1e-30f) { float ih = 1.0f / hyp; sn = num * ih; cs = den * ih; }
        else { sn = 0.0f; cs = 1.0f; }
        float drx = c0[0]-c3[0], dry = c0[1]-c3[1], drz = c0[2]-c3[2];
        float dl = sqrtf(fmaxf(drx*drx + dry*dry + drz*drz, 1e-12f));
        float il = 1.0f / dl;
        sSn[r] = sn; sCs[r] = cs; sDl[r] = dl;
        sDh[r][0] = drx * il; sDh[r][1] = dry * il; sDh[r][2] = drz * il;
    }
    __syncthreads();   // B1: geometry ready (E loads drained here too)

    // ---- h0 = leaky(g + rank-4 features + b0) -> SH0, vectorized 16B stores ----
    {
        float g[8];
        #pragma unroll
        for (int j = 0; j < 8; ++j)
            g[j] = (float)e0[j] + (float)e1[j] + (float)e2[j] + (float)e3[j] + b0v[j];
        #pragma unroll
        for (int t = 0; t < 4; ++t) {
            int r = p * 4 + t;
            float tvv = (t == 0) ? tv0 : (t == 1) ? tv1 : (t == 2) ? tv2 : tv3;
            float sn = sSn[r], cs = sCs[r], dl = sDl[r];
            bf16 hv[8];
            #pragma unroll
            for (int j = 0; j < 8; ++j) {
                float v = g[j] + tvv * w512v[j] + sn * w513v[j] + cs * w514v[j] + dl * w515v[j];
                v = fmaxf(v, LEAKY * v);
                hv[j] = (bf16)v;
            }
            *(bf16x8*)(&SH0(r, s8 * 8)) = *(const bf16x8*)hv;
        }
    }
    __syncthreads();   // B2: H0 ready

    const int wv = tid >> 6, lane = tid & 63;
    const int fr = lane & 15, quad = lane >> 4;
    const int m2 = (wv & 3) * 2;   // first of 2 M-tiles for phases 3/4
    const int nh = wv >> 2;        // N-half (cols nh*64..+63)

    // ---- phase 3: h1 = leaky(h0 @ W1 + b1); read SH0, write SH1 ----
    #pragma unroll
    for (int s = 0; s < 2; ++s) {
        f32x4 hacc[4];
        #pragma unroll
        for (int nt = 0; nt < 4; ++nt) hacc[nt] = (f32x4){0.f,0.f,0.f,0.f};
        const bf16* aRow = &SH0((m2 + s) * 16 + fr, quad * 8);
        const bf16* w1b = W1sw + lane * 8;
        #pragma unroll
        for (int kc = 0; kc < 4; ++kc) {
            bf16x8 aF = *(const bf16x8*)(aRow + kc * 32);
            #pragma unroll
            for (int nt = 0; nt < 4; ++nt) {
                bf16x8 bF = *(const bf16x8*)(w1b + ((nh * 4 + nt) * 4 + kc) * 512);
                hacc[nt] = __builtin_amdgcn_mfma_f32_16x16x32_bf16(aF, bF, hacc[nt], 0, 0, 0);
            }
        }
        #pragma unroll
        for (int nt = 0; nt < 4; ++nt) {
            int j = (nh * 4 + nt) * 16 + fr;
            float bb = b1[j];
            #pragma unroll
            for (int reg = 0; reg < 4; ++reg) {
                int r = (m2 + s) * 16 + quad * 4 + reg;
                float v = hacc[nt][reg] + bb;
                v = fmaxf(v, LEAKY * v);
                SH1(r, j) = (bf16)v;
            }
        }
    }
    __syncthreads();   // B3: H1 ready, H0 reads complete

    // ---- phase 4: h2 = leaky(h1 @ W2 + b2); read SH1, write SH0 ----
    #pragma unroll
    for (int s = 0; s < 2; ++s) {
        f32x4 hacc[4];
        #pragma unroll
        for (int nt = 0; nt < 4; ++nt) hacc[nt] = (f32x4){0.f,0.f,0.f,0.f};
        const bf16* aRow = &SH1((m2 + s) * 16 + fr, quad * 8);
        const bf16* w2b = W2sw + lane * 8;
        #pragma unroll
        for (int kc = 0; kc < 4; ++kc) {
            bf16x8 aF = *(const bf16x8*)(aRow + kc * 32);
            #pragma unroll
            for (int nt = 0; nt < 4; ++nt) {
                bf16x8 bF = *(const bf16x8*)(w2b + ((nh * 4 + nt) * 4 + kc) * 512);
                hacc[nt] = __builtin_amdgcn_mfma_f32_16x16x32_bf16(aF, bF, hacc[nt], 0, 0, 0);
            }
        }
        #pragma unroll
        for (int nt = 0; nt < 4; ++nt) {
            int j = (nh * 4 + nt) * 16 + fr;
            float bb = b2[j];
            #pragma unroll
            for (int reg = 0; reg < 4; ++reg) {
                int r = (m2 + s) * 16 + quad * 4 + reg;
                float v = hacc[nt][reg] + bb;
                v = fmaxf(v, LEAKY * v);
                SH0(r, j) = (bf16)v;
            }
        }
    }
    __syncthreads();   // B4: H2 ready

    // ---- phase 5: delta = h2 @ W3 + b3 (zero-padded to 16 cols); all 8 waves ----
    {
        f32x4 dacc = {0.f,0.f,0.f,0.f};
        const bf16* aRow = &SH0(wv * 16 + fr, quad * 8);
        const bf16* w3b = W3sw + lane * 8;
        #pragma unroll
        for (int kc = 0; kc < 4; ++kc) {
            bf16x8 aF = *(const bf16x8*)(aRow + kc * 32);
            bf16x8 bF = *(const bf16x8*)(w3b + kc * 512);
            dacc = __builtin_amdgcn_mfma_f32_16x16x32_bf16(aF, bF, dacc, 0, 0, 0);
        }
        if (fr < 2) {
            float bb = b3[fr];
            #pragma unroll
            for (int reg = 0; reg < 4; ++reg)
                sDelta[wv * 16 + quad * 4 + reg][fr] = dacc[reg] + bb;
        }
    }
    __syncthreads();   // B5: delta ready

    // ---- phase 6: scatter-add (6 atomics per row, 768 total) ----
    for (int idx = tid; idx < ROWS * 6; idx += 512) {
        int r = idx / 6, c = idx % 6;
        int pp = r >> 2, t = r & 3;
        int side = c / 3, ax = c % 3;
        int node = sNodes[pp][side ? 3 : 0];
        float dval = side ? 0.5f * sDelta[r][1] : -0.5f * sDelta[r][0];
        atomicAdd(out + node * 12 + t * 3 + ax, dval * sDh[r][ax]);
    }
    #undef SH0
    #undef SH1
}

extern "C" void kernel_launch(void* const* d_in, const int* in_sizes, int n_in,
                              void* d_out, int out_size, void* d_ws, size_t ws_size,
                              hipStream_t stream) {
    const float* coords  = (const float*)d_in[0];
    const int*   propers = (const int*)d_in[1];
    const float* encoded = (const float*)d_in[2];
    const float* tvec    = (const float*)d_in[3];
    const float* answer  = (const float*)d_in[4];
    const float* W0 = (const float*)d_in[5];
    const float* b0 = (const float*)d_in[6];
    const float* W1 = (const float*)d_in[7];
    const float* b1 = (const float*)d_in[8];
    const float* W2 = (const float*)d_in[9];
    const float* b2 = (const float*)d_in[10];
    const float* W3 = (const float*)d_in[11];
    const float* b3 = (const float*)d_in[12];
    float* out = (float*)d_out;
    char* ws = (char*)d_ws;
    bf16* encB = (bf16*)(ws + OFF_ENCB);
    bf16* W0sw = (bf16*)(ws + OFF_W0SW);
    bf16* W1sw = (bf16*)(ws + OFF_W1SW);
    bf16* W2sw = (bf16*)(ws + OFF_W2SW);
    bf16* W3sw = (bf16*)(ws + OFF_W3SW);
    bf16* E    = (bf16*)(ws + OFF_E);

    int prep_blocks = (PR_TOTAL + 255) / 256;
    prep_kernel<<<prep_blocks, 256, 0, stream>>>(encoded, W0, W1, W2, W3, answer,
                                                 encB, W0sw, W1sw, W2sw, W3sw, out);
    prep_e_kernel<<<(NN + 15) / 16, 512, 0, stream>>>(encB, W0sw, E);
    main_kernel<<<PP / PB, 512, 0, stream>>>(coords, propers, tvec, W0, b0, b1, b2, b3,
                                             E, W1sw, W2sw, W3sw, out);
}